// Round 1
// 1500.165 us; speedup vs baseline: 1.0076x; 1.0076x over previous
//
#include <hip/hip_runtime.h>

// MFMA split-FP16 jet-propagation PINN.
// Jet comps: 0:val 1:x 2:y 3:t 4:xx 5:xy 6:yy 7:xt 8:yt 9:xxx 10:xxy 11:xyy 12:yyy
// J in LDS: PACKED rows m = sample*13 + comp, k = hidden neuron; f16 hi+lo planes.
// Row layout: 32 chunks of 8 f16 (16 B); phys chunk = logical ^ (m&15)  (bank swizzle).
// Per layer: U = J * W^T via mfma_f32_16x16x32_f16, 3 passes (hi*hi, hi*lo, lo*hi).
// R15 (1511 us): scalarized B addressing. Counter audit: MfmaUtil 45% is TRUE CU-level
// util (887 TF), but VALUBusy 50% is an any-of-4-SIMD statistic -> true VALU ~16%.
// Nothing saturated => LATENCY-bound at 12 waves/CU (LDS caps 3 blocks/CU).
// R16: TS 4->3 (J = 39 rows = 39.9 KB -> 4 blocks/CU, 16 waves/CU) + FUSED kloop:
// one 3-M-tile K-sweep per layer (acc[3][4], 48 VGPR) streaming B ONCE per layer
// (was twice), 2 barriers/layer (was 3). Per-sample math identical.

#define N_PTS 65536
#define HID   256
#define TS    3

typedef _Float16 half_t;
typedef __attribute__((ext_vector_type(8))) _Float16 half8;
typedef __attribute__((ext_vector_type(4))) float floatx4;

#define J_HI   0
#define J_LO   19968              // 39 packed rows * 512 B per plane
#define REDBUF 39936              // 192 B head partials
#define LDS_BYTES (REDBUF + 192)  // 40128 B -> 4 blocks/CU

struct alignas(4) hpair { half_t a, b; };

__device__ __forceinline__ float fast_tanh(float x) {
    float e = __builtin_amdgcn_exp2f(x * 2.885390081777927f);
    return 1.f - 2.f * __builtin_amdgcn_rcpf(e + 1.f);
}

__device__ __forceinline__ void tanh_jet(const float* u, float* h) {
    const float f  = fast_tanh(u[0]);
    const float f1 = 1.f - f * f;
    const float f2 = -2.f * f * f1;
    const float f3 = -2.f * f1 * f1 + 4.f * f * f * f1;
    const float ux = u[1], uy = u[2], ut = u[3];
    const float uxx = u[4], uxy = u[5], uyy = u[6], uxt = u[7], uyt = u[8];
    h[0] = f;
    h[1] = f1 * ux;  h[2] = f1 * uy;  h[3] = f1 * ut;
    h[4] = f2 * ux * ux + f1 * uxx;
    h[5] = f2 * ux * uy + f1 * uxy;
    h[6] = f2 * uy * uy + f1 * uyy;
    h[7] = f2 * ux * ut + f1 * uxt;
    h[8] = f2 * uy * ut + f1 * uyt;
    h[9]  = f3 * ux * ux * ux + 3.f * f2 * ux * uxx + f1 * u[9];
    h[10] = f3 * ux * ux * uy + f2 * (uxx * uy + 2.f * uxy * ux) + f1 * u[10];
    h[11] = f3 * ux * uy * uy + f2 * (uyy * ux + 2.f * uxy * uy) + f1 * u[11];
    h[12] = f3 * uy * uy * uy + 3.f * f2 * uy * uyy + f1 * u[12];
}

// ---- prep: split W2, W3, Wp1, Wd1 into f16 hi/lo planes, FRAGMENT-ORDERED ----
// (n,k) -> addr = ((ntile*8 + kb)*64 + q*16 + nl)*8 + e  -> wave loads 1 KB contiguous
__global__ void prep_w(const float* __restrict__ W2, const float* __restrict__ W3,
                       const float* __restrict__ Wp1, const float* __restrict__ Wd1,
                       half_t* __restrict__ ws) {
    int idx = blockIdx.x * 256 + threadIdx.x;
#pragma unroll
    for (int r = 0; r < 4; ++r) {
        int e = idx + r * 65536;
        int m = e >> 16, i = e & 65535;
        const float* src = (m == 0) ? W2 : (m == 1) ? W3 : (m == 2) ? Wp1 : Wd1;
        float w = src[i];
        half_t hi = (half_t)w;
        half_t lo = (half_t)(w - (float)hi);
        int n = i >> 8, k = i & 255;
        int addr = (((n >> 4) * 8 + (k >> 5)) * 64 + ((k >> 3) & 3) * 16 + (n & 15)) * 8
                   + (k & 7);
        ws[m * 131072 + addr] = hi;
        ws[m * 131072 + 65536 + addr] = lo;
    }
}

// coalesced fragment load, SCALAR base: bh/bl are wave-uniform (readfirstlane),
// vo = lane*8 halfs is the only per-lane term -> SGPR-base global_load.
__device__ __forceinline__ void load_B(const half_t* bh, const half_t* bl,
                                       int vo, int kb,
                                       half8 (&Bh)[4], half8 (&Bl)[4]) {
#pragma unroll
    for (int nt = 0; nt < 4; ++nt) {
        int off = nt * 4096 + kb * 512 + vo;   // halfs; nt,kb uniform
        Bh[nt] = *(const half8*)(bh + off);
        Bl[nt] = *(const half8*)(bl + off);
    }
}

// shuffle-transpose epilogue (no LDS stage): 4x4 transpose among lanes {q,same nl}
// via two shfl_xor butterflies; then tanh_jet; write J' hi/lo in place. All 3 tiles.
__device__ __forceinline__ void epilogue(char* __restrict__ smem,
                                         const float* __restrict__ bias,
                                         int wave, int lane, int q,
                                         floatx4 (&acc)[3][4]) {
    const int n = wave * 64 + lane;
    const float bn = bias[n];
#pragma unroll
    for (int mt = 0; mt < 3; ++mt) {
        float a0[4][4], e[4][4];
#pragma unroll
        for (int j = 0; j < 4; ++j)
#pragma unroll
            for (int r = 0; r < 4; ++r) {
                float part = __shfl_xor(acc[mt][j ^ 1][r], 16, 64);
                a0[j][r] = ((j ^ q) & 1) ? part : acc[mt][j][r];
            }
#pragma unroll
        for (int j = 0; j < 4; ++j)
#pragma unroll
            for (int r = 0; r < 4; ++r) {
                float part = __shfl_xor(a0[j ^ 2][r], 32, 64);
                e[j][r] = ((j ^ q) & 2) ? part : a0[j][r];
            }
        // e[Q][R] = C row 4Q+R of column n
        float u[13], h[13];
#pragma unroll
        for (int c = 0; c < 13; ++c) u[c] = e[c >> 2][c & 3];
        u[0] += bn;
        tanh_jet(u, h);
#pragma unroll
        for (int c = 0; c < 13; ++c) {
            int m = mt * 13 + c;
            int off = m * 512 + (((n >> 3) ^ (m & 15)) << 4) + ((n & 7) << 1);
            half_t hi = (half_t)h[c];
            *(half_t*)(smem + J_HI + off) = hi;
            *(half_t*)(smem + J_LO + off) = (half_t)(h[c] - (float)hi);
        }
    }
}

// one full layer, FUSED: single K-sweep over all 3 M-tiles with one B stream,
// then barrier (all J reads done), epilogue (overwrite J), barrier (publish).
__device__ __forceinline__ void layer(char* __restrict__ smem,
                                      const half_t* bh, const half_t* bl,
                                      const float* __restrict__ bias,
                                      int wave, int lane, int vo, int q, int anl,
                                      floatx4 (&acc)[3][4]) {
#pragma unroll
    for (int mt = 0; mt < 3; ++mt)
#pragma unroll
        for (int nt = 0; nt < 4; ++nt) acc[mt][nt] = floatx4{0.f, 0.f, 0.f, 0.f};
#pragma unroll 1
    for (int kb = 0; kb < 8; ++kb) {
        half8 Bh[4], Bl[4];
        load_B(bh, bl, vo, kb, Bh, Bl);
#pragma unroll
        for (int mt = 0; mt < 3; ++mt) {
            const int m = mt * 13 + anl;
            const int pc = (((kb * 4 + q) ^ (m & 15)) << 4) + m * 512;
            half8 Ah = *(const half8*)(smem + J_HI + pc);
            half8 Al = *(const half8*)(smem + J_LO + pc);
#pragma unroll
            for (int nt = 0; nt < 4; ++nt) {
                acc[mt][nt] = __builtin_amdgcn_mfma_f32_16x16x32_f16(Ah, Bh[nt], acc[mt][nt], 0, 0, 0);
                acc[mt][nt] = __builtin_amdgcn_mfma_f32_16x16x32_f16(Ah, Bl[nt], acc[mt][nt], 0, 0, 0);
                acc[mt][nt] = __builtin_amdgcn_mfma_f32_16x16x32_f16(Al, Bh[nt], acc[mt][nt], 0, 0, 0);
            }
        }
    }
    __syncthreads();                 // all waves' J reads done before overwrite
    epilogue(smem, bias, wave, lane, q, acc);
    __syncthreads();                 // publish new J
}

__global__ __launch_bounds__(256, 4) void pinn_mfma(
    const float* __restrict__ gx, const float* __restrict__ gy, const float* __restrict__ gt,
    const float* __restrict__ W1, const float* __restrict__ b1,
    const float* __restrict__ b2, const float* __restrict__ b3,
    const float* __restrict__ bp1, const float* __restrict__ Wp2,
    const float* __restrict__ bd1, const float* __restrict__ Wd2,
    const float* __restrict__ bd2,
    const float* __restrict__ lam1p, const float* __restrict__ lam2p,
    const half_t* __restrict__ wsw, float* __restrict__ out) {
    extern __shared__ char smem[];
    const int t = threadIdx.x;
    const int wave = t >> 6, lane = t & 63;
    const int q = lane >> 4, nl = lane & 15;
    const int anl = nl < 13 ? nl : 12;   // packed-13 row clamp (dup rows ignored in C)
    const int base = blockIdx.x * TS;
    // wave-uniform B base offset (halfs) + per-lane offset: scalarized addressing
    const int wo = __builtin_amdgcn_readfirstlane(wave) * 16384;
    const int vo = lane * 8;

    // ---------------- Layer 1: (x,y,t) -> J1 ----------------
#pragma unroll 1
    for (int ii = 0; ii < 2; ++ii) {
        int p = ii * 256 + t;               // (sample, j-pair) 0..TS*128-1
        if (p < TS * 128) {
            int s = p >> 7, j = (p & 127) * 2;
            int gi = base + s; if (gi >= N_PTS) gi = N_PTS - 1;   // tail clamp
            float qx = gx[gi], qy = gy[gi], qt = gt[gi];
            float hv[2][13];
#pragma unroll
            for (int d = 0; d < 2; ++d) {
                int jj = j + d;
                float w0 = W1[3 * jj], w1 = W1[3 * jj + 1], w2 = W1[3 * jj + 2];
                float f = fast_tanh(w0 * qx + w1 * qy + w2 * qt + b1[jj]);
                float f1 = 1.f - f * f;
                float f2c = -2.f * f * f1;
                float f3c = -2.f * f1 * f1 + 4.f * f * f * f1;
                float* h = hv[d];
                h[0] = f; h[1] = f1 * w0; h[2] = f1 * w1; h[3] = f1 * w2;
                h[4] = f2c * w0 * w0; h[5] = f2c * w0 * w1; h[6] = f2c * w1 * w1;
                h[7] = f2c * w0 * w2; h[8] = f2c * w1 * w2;
                h[9]  = f3c * w0 * w0 * w0; h[10] = f3c * w0 * w0 * w1;
                h[11] = f3c * w0 * w1 * w1; h[12] = f3c * w1 * w1 * w1;
            }
#pragma unroll
            for (int c = 0; c < 13; ++c) {
                int m = s * 13 + c;
                int off = m * 512 + ((((j) >> 3) ^ (m & 15)) << 4) + ((j & 7) << 1);
                half_t hA = (half_t)hv[0][c], hB = (half_t)hv[1][c];
                *(hpair*)(smem + J_HI + off) = hpair{hA, hB};
                half_t lA = (half_t)(hv[0][c] - (float)hA);
                half_t lB = (half_t)(hv[1][c] - (float)hB);
                *(hpair*)(smem + J_LO + off) = hpair{lA, lB};
            }
        }
    }
    __syncthreads();

    floatx4 acc[3][4];

    // ---------------- Layers 2, 3 ----------------
    layer(smem, wsw + wo,          wsw + 65536 + wo,          b2,
          wave, lane, vo, q, anl, acc);
    layer(smem, wsw + 131072 + wo, wsw + 131072 + 65536 + wo, b3,
          wave, lane, vo, q, anl, acc);

    // ---------------- Data head (uses J3 comps 0..2), A read directly from J ----
    {
        // single M-tile: logical row r = nl = 4s+c -> J row s*13+c (c<3; dummies clamped)
        int sh = nl >> 2, ch = nl & 3;
        int sc = (sh < TS) ? sh : 0;             // TS=3: row 3 dup of sample 0 (unread)
        int mh = sc * 13 + ((ch == 3) ? 0 : ch);
        floatx4 hacc[4];
#pragma unroll
        for (int nt = 0; nt < 4; ++nt) hacc[nt] = floatx4{0.f, 0.f, 0.f, 0.f};
        const half_t* Dhi = wsw + 3 * 131072 + wo;
        const half_t* Dlo = Dhi + 65536;
#pragma unroll 1
        for (int kb = 0; kb < 8; ++kb) {
            half8 Bh[4], Bl[4];
            load_B(Dhi, Dlo, vo, kb, Bh, Bl);
            int pc = (((kb * 4 + q) ^ (mh & 15)) << 4) + mh * 512;
            half8 Ah = *(const half8*)(smem + J_HI + pc);
            half8 Al = *(const half8*)(smem + J_LO + pc);
#pragma unroll
            for (int nt = 0; nt < 4; ++nt) {
                hacc[nt] = __builtin_amdgcn_mfma_f32_16x16x32_f16(Ah, Bh[nt], hacc[nt], 0, 0, 0);
                hacc[nt] = __builtin_amdgcn_mfma_f32_16x16x32_f16(Ah, Bl[nt], hacc[nt], 0, 0, 0);
                hacc[nt] = __builtin_amdgcn_mfma_f32_16x16x32_f16(Al, Bh[nt], hacc[nt], 0, 0, 0);
            }
        }
        // head epilogue: C row = q*4 + reg -> sample s = q, comp c = reg (0..2 used)
        {
            float pp = 0, up = 0, vp = 0;
#pragma unroll
            for (int nt = 0; nt < 4; ++nt) {
                int n = wave * 64 + nt * 16 + nl;
                floatx4 a = hacc[nt];
                float f = fast_tanh(a.x + bd1[n]);
                float f1 = 1.f - f * f;
                float hdx = f1 * a.y, hdy = f1 * a.z;
                float w0 = Wd2[n], w1 = Wd2[HID + n];
                pp += w1 * f;
                up += w0 * hdy;
                vp -= w0 * hdx;
            }
            float* rb = (float*)(smem + REDBUF);
#pragma unroll
            for (int msk = 1; msk < 16; msk <<= 1) {
                pp += __shfl_xor(pp, msk, 64);
                up += __shfl_xor(up, msk, 64);
                vp += __shfl_xor(vp, msk, 64);
            }
            if (nl == 0) {                  // sample s = q (q==3 partials never read)
                rb[(q * 4 + wave) * 3 + 0] = pp;
                rb[(q * 4 + wave) * 3 + 1] = up;
                rb[(q * 4 + wave) * 3 + 2] = vp;
            }
        }
        __syncthreads();
        if (t < TS && base + t < N_PTS) {
            const float* rb = (const float*)(smem + REDBUF);
            float P = 0, U = 0, V = 0;
#pragma unroll
            for (int w = 0; w < 4; ++w) {
                P += rb[(t * 4 + w) * 3 + 0];
                U += rb[(t * 4 + w) * 3 + 1];
                V += rb[(t * 4 + w) * 3 + 2];
            }
            out[0 * N_PTS + base + t] = P + bd2[1];
            out[1 * N_PTS + base + t] = U;
            out[2 * N_PTS + base + t] = V;
        }
    }

    // ---------------- PDE-head layer Wp1 ----------------
    layer(smem, wsw + 2 * 131072 + wo, wsw + 2 * 131072 + 65536 + wo, bp1,
          wave, lane, vo, q, anl, acc);

    // ---------------- PDE reduction from J4 ----------------
    {
        int s = t >> 5, g = t & 31;
        if (s < TS) {
            float wr0[8], wr1[8];
#pragma unroll
            for (int i = 0; i < 8; ++i) {
                wr0[i] = Wp2[g + 32 * i];
                wr1[i] = Wp2[HID + g + 32 * i];
            }
            float S[13];
#pragma unroll
            for (int c = 0; c < 13; ++c) {
                int m = s * 13 + c;
                float p = 0.f;
#pragma unroll
                for (int i = 0; i < 8; ++i) {
                    int k = g + 32 * i;
                    int off = m * 512 + (((k >> 3) ^ (m & 15)) << 4) + ((k & 7) << 1);
                    float hvv = (float)*(const half_t*)(smem + J_HI + off) +
                                (float)*(const half_t*)(smem + J_LO + off);
                    p += hvv * wr0[i];
                }
#pragma unroll
                for (int msk = 1; msk < 32; msk <<= 1) p += __shfl_xor(p, msk, 64);
                S[c] = p;
            }
            float px = 0.f, py = 0.f;
#pragma unroll
            for (int i = 0; i < 8; ++i) {
                int k = g + 32 * i;
                int m1 = s * 13 + 1, m2 = s * 13 + 2;
                int o1 = m1 * 512 + (((k >> 3) ^ (m1 & 15)) << 4) + ((k & 7) << 1);
                int o2 = m2 * 512 + (((k >> 3) ^ (m2 & 15)) << 4) + ((k & 7) << 1);
                px += ((float)*(const half_t*)(smem + J_HI + o1) +
                       (float)*(const half_t*)(smem + J_LO + o1)) * wr1[i];
                py += ((float)*(const half_t*)(smem + J_HI + o2) +
                       (float)*(const half_t*)(smem + J_LO + o2)) * wr1[i];
            }
#pragma unroll
            for (int msk = 1; msk < 32; msk <<= 1) {
                px += __shfl_xor(px, msk, 64);
                py += __shfl_xor(py, msk, 64);
            }
            if (g == 0 && base + s < N_PTS) {
                const float lam1 = lam1p[0], lam2 = lam2p[0];
                const float u_ = S[2], v_ = -S[1];
                const float u_x = S[5], u_y = S[6], u_t = S[8];
                const float v_x = -S[4], v_y = -S[5], v_t = -S[7];
                const float u_xx = S[10], u_yy = S[12];
                const float v_xx = -S[9], v_yy = -S[11];
                const float f_ = lam1 * (u_t + u_ * u_x + v_ * u_y) + px - lam2 * (u_xx + u_yy);
                const float g_ = lam1 * (v_t + u_ * v_x + v_ * v_y) + py - lam2 * (v_xx + v_yy);
                out[3 * N_PTS + base + s] = f_;
                out[4 * N_PTS + base + s] = g_;
            }
        }
    }
}

extern "C" void kernel_launch(void* const* d_in, const int* in_sizes, int n_in,
                              void* d_out, int out_size, void* d_ws, size_t ws_size,
                              hipStream_t stream) {
    const float* x   = (const float*)d_in[0];
    const float* y   = (const float*)d_in[1];
    const float* tt  = (const float*)d_in[2];
    const float* W1  = (const float*)d_in[6];
    const float* b1  = (const float*)d_in[7];
    const float* W2  = (const float*)d_in[8];
    const float* b2  = (const float*)d_in[9];
    const float* W3  = (const float*)d_in[10];
    const float* b3  = (const float*)d_in[11];
    const float* Wp1 = (const float*)d_in[12];
    const float* bp1 = (const float*)d_in[13];
    const float* Wp2 = (const float*)d_in[14];
    const float* Wd1 = (const float*)d_in[16];
    const float* bd1 = (const float*)d_in[17];
    const float* Wd2 = (const float*)d_in[18];
    const float* bd2 = (const float*)d_in[19];
    const float* l1  = (const float*)d_in[20];
    const float* l2  = (const float*)d_in[21];
    float* out = (float*)d_out;
    half_t* wsw = (half_t*)d_ws;   // needs 4 * 256 KB = 1 MB

    prep_w<<<256, 256, 0, stream>>>(W2, W3, Wp1, Wd1, wsw);

    (void)hipFuncSetAttribute((const void*)pinn_mfma,
                              hipFuncAttributeMaxDynamicSharedMemorySize,
                              (int)LDS_BYTES);
    pinn_mfma<<<(N_PTS + TS - 1) / TS, 256, LDS_BYTES, stream>>>(
        x, y, tt, W1, b1, b2, b3, bp1, Wp2, bd1, Wd2, bd2, l1, l2, wsw, out);
}

// Round 2
// 1278.030 us; speedup vs baseline: 1.1828x; 1.1738x over previous
//
#include <hip/hip_runtime.h>

// MFMA split-FP16 jet-propagation PINN.
// Jet comps: 0:val 1:x 2:y 3:t 4:xx 5:xy 6:yy 7:xt 8:yt 9:xxx 10:xxy 11:xyy 12:yyy
// J in LDS: PACKED rows m = sample*13 + comp, k = hidden neuron; f16 hi+lo planes.
// Row layout: 32 chunks of 8 f16 (16 B); phys chunk = logical ^ (m&15)  (bank swizzle).
// Per layer: U = J * W^T via mfma_f32_16x16x32_f16, 3 passes (hi*hi, hi*lo, lo*hi).
// R16 (1450 us): TS=3, 4 blocks/CU, fused 3-tile kloop. Issue-budget audit:
// MFMA 4.7k cyc + VALU ~9.2k cyc (2 slots/instr) + ds ~1.5k per wave ~= oversubscribed
// SIMD issue port -> VALU INSTRUCTION COUNT is the binding resource.
// R17: cut issue slots. (1) permlane16/32_swap dual-writeback transpose: 16 instr/tile
// replaces 32 shfl(ds) + 32 cndmask. (2) XOR-fold swizzled J addressing (disjoint bit
// ranges -> lanebase ^ const + imm ds offsets), per-mt bases hoisted out of kb loop.
// (3) PDE tail: ds_read_b128 per chunk (2 loads/comp vs 16 scalar), float4 Wp2,
// px/py folded into c==1/2. (4) kb=0 B-load peeled above acc-zero (free ~100cy hide).

#define N_PTS 65536
#define HID   256
#define TS    3

typedef _Float16 half_t;
typedef __attribute__((ext_vector_type(8))) _Float16 half8;
typedef __attribute__((ext_vector_type(4))) float floatx4;

#define J_HI   0
#define J_LO   19968              // 39 packed rows * 512 B per plane
#define REDBUF 39936              // 192 B head partials
#define LDS_BYTES (REDBUF + 192)  // 40128 B -> 4 blocks/CU

struct alignas(4) hpair { half_t a, b; };

__device__ __forceinline__ float fast_tanh(float x) {
    float e = __builtin_amdgcn_exp2f(x * 2.885390081777927f);
    return 1.f - 2.f * __builtin_amdgcn_rcpf(e + 1.f);
}

__device__ __forceinline__ void tanh_jet(const float* u, float* h) {
    const float f  = fast_tanh(u[0]);
    const float f1 = 1.f - f * f;
    const float f2 = -2.f * f * f1;
    const float f3 = -2.f * f1 * f1 + 4.f * f * f * f1;
    const float ux = u[1], uy = u[2], ut = u[3];
    const float uxx = u[4], uxy = u[5], uyy = u[6], uxt = u[7], uyt = u[8];
    h[0] = f;
    h[1] = f1 * ux;  h[2] = f1 * uy;  h[3] = f1 * ut;
    h[4] = f2 * ux * ux + f1 * uxx;
    h[5] = f2 * ux * uy + f1 * uxy;
    h[6] = f2 * uy * uy + f1 * uyy;
    h[7] = f2 * ux * ut + f1 * uxt;
    h[8] = f2 * uy * ut + f1 * uyt;
    h[9]  = f3 * ux * ux * ux + 3.f * f2 * ux * uxx + f1 * u[9];
    h[10] = f3 * ux * ux * uy + f2 * (uxx * uy + 2.f * uxy * ux) + f1 * u[10];
    h[11] = f3 * ux * uy * uy + f2 * (uyy * ux + 2.f * uxy * uy) + f1 * u[11];
    h[12] = f3 * uy * uy * uy + 3.f * f2 * uy * uyy + f1 * u[12];
}

// ---- prep: split W2, W3, Wp1, Wd1 into f16 hi/lo planes, FRAGMENT-ORDERED ----
// (n,k) -> addr = ((ntile*8 + kb)*64 + q*16 + nl)*8 + e  -> wave loads 1 KB contiguous
__global__ void prep_w(const float* __restrict__ W2, const float* __restrict__ W3,
                       const float* __restrict__ Wp1, const float* __restrict__ Wd1,
                       half_t* __restrict__ ws) {
    int idx = blockIdx.x * 256 + threadIdx.x;
#pragma unroll
    for (int r = 0; r < 4; ++r) {
        int e = idx + r * 65536;
        int m = e >> 16, i = e & 65535;
        const float* src = (m == 0) ? W2 : (m == 1) ? W3 : (m == 2) ? Wp1 : Wd1;
        float w = src[i];
        half_t hi = (half_t)w;
        half_t lo = (half_t)(w - (float)hi);
        int n = i >> 8, k = i & 255;
        int addr = (((n >> 4) * 8 + (k >> 5)) * 64 + ((k >> 3) & 3) * 16 + (n & 15)) * 8
                   + (k & 7);
        ws[m * 131072 + addr] = hi;
        ws[m * 131072 + 65536 + addr] = lo;
    }
}

// coalesced fragment load, SCALAR base: bh/bl are wave-uniform (readfirstlane),
// vo = lane*8 halfs is the only per-lane term -> SGPR-base global_load.
__device__ __forceinline__ void load_B(const half_t* bh, const half_t* bl,
                                       int vo, int kb,
                                       half8 (&Bh)[4], half8 (&Bl)[4]) {
#pragma unroll
    for (int nt = 0; nt < 4; ++nt) {
        int off = nt * 4096 + kb * 512 + vo;   // halfs; nt,kb uniform
        Bh[nt] = *(const half8*)(bh + off);
        Bl[nt] = *(const half8*)(bl + off);
    }
}

// one kb step: 3 A-tile pairs (precomputed row bases, xor-folded chunk), 36 MFMAs
__device__ __forceinline__ void mfma_phase(const char* __restrict__ smem,
                                           const int (&mx)[3], const int (&mr)[3],
                                           int kb, int q,
                                           const half8 (&Bh)[4], const half8 (&Bl)[4],
                                           floatx4 (&acc)[3][4]) {
    const int kq = (kb * 4 + q) << 4;
#pragma unroll
    for (int mt = 0; mt < 3; ++mt) {
        const int a = mr[mt] + (kq ^ mx[mt]);
        half8 Ah = *(const half8*)(smem + J_HI + a);
        half8 Al = *(const half8*)(smem + J_LO + a);
#pragma unroll
        for (int nt = 0; nt < 4; ++nt) {
            acc[mt][nt] = __builtin_amdgcn_mfma_f32_16x16x32_f16(Ah, Bh[nt], acc[mt][nt], 0, 0, 0);
            acc[mt][nt] = __builtin_amdgcn_mfma_f32_16x16x32_f16(Ah, Bl[nt], acc[mt][nt], 0, 0, 0);
            acc[mt][nt] = __builtin_amdgcn_mfma_f32_16x16x32_f16(Al, Bh[nt], acc[mt][nt], 0, 0, 0);
        }
    }
}

// transpose epilogue via gfx950 dual-writeback permlane swaps (16 instr/tile):
// stage1 swaps 16-lane rows (== shfl_xor 16 + select), stage2 swaps 32-lane rows.
// Then tanh_jet; write J' hi/lo in place with xor-folded addressing.
__device__ __forceinline__ void epilogue(char* __restrict__ smem,
                                         const float* __restrict__ bias,
                                         int wave, int lane,
                                         floatx4 (&acc)[3][4]) {
    const int n = wave * 64 + lane;
    const float bn = bias[n];
    const int lanebase = ((n >> 3) << 4) | ((n & 7) << 1);
#pragma unroll
    for (int mt = 0; mt < 3; ++mt) {
        float tv[4][4];
#pragma unroll
        for (int j = 0; j < 4; ++j)
#pragma unroll
            for (int r = 0; r < 4; ++r) tv[j][r] = acc[mt][j][r];
#pragma unroll
        for (int r = 0; r < 4; ++r) {
            asm("v_permlane16_swap_b32 %0, %1" : "+v"(tv[0][r]), "+v"(tv[1][r]));
            asm("v_permlane16_swap_b32 %0, %1" : "+v"(tv[2][r]), "+v"(tv[3][r]));
            asm("v_permlane32_swap_b32 %0, %1" : "+v"(tv[0][r]), "+v"(tv[2][r]));
            asm("v_permlane32_swap_b32 %0, %1" : "+v"(tv[1][r]), "+v"(tv[3][r]));
        }
        // tv[Q][R] = C row 4Q+R of column n
        float u[13], h[13];
#pragma unroll
        for (int c = 0; c < 13; ++c) u[c] = tv[c >> 2][c & 3];
        u[0] += bn;
        tanh_jet(u, h);
#pragma unroll
        for (int c = 0; c < 13; ++c) {
            const int m = mt * 13 + c;
            const int off = m * 512 + (lanebase ^ ((m & 15) << 4));
            half_t hi = (half_t)h[c];
            *(half_t*)(smem + J_HI + off) = hi;
            *(half_t*)(smem + J_LO + off) = (half_t)(h[c] - (float)hi);
        }
    }
}

// one full layer, FUSED: single K-sweep over all 3 M-tiles with one B stream.
// kb=0 B-load peeled above acc-zero so the first L2 latency hides under 48 AGPR inits.
__device__ __forceinline__ void layer(char* __restrict__ smem,
                                      const half_t* bh, const half_t* bl,
                                      const float* __restrict__ bias,
                                      int wave, int lane, int vo, int q, int anl,
                                      floatx4 (&acc)[3][4]) {
    int mx[3], mr[3];
#pragma unroll
    for (int mt = 0; mt < 3; ++mt) {
        const int m = mt * 13 + anl;
        mx[mt] = (m & 15) << 4;
        mr[mt] = m * 512;
    }
    half8 Bh[4], Bl[4];
    load_B(bh, bl, vo, 0, Bh, Bl);
#pragma unroll
    for (int mt = 0; mt < 3; ++mt)
#pragma unroll
        for (int nt = 0; nt < 4; ++nt) acc[mt][nt] = floatx4{0.f, 0.f, 0.f, 0.f};
    mfma_phase(smem, mx, mr, 0, q, Bh, Bl, acc);
#pragma unroll 1
    for (int kb = 1; kb < 8; ++kb) {
        load_B(bh, bl, vo, kb, Bh, Bl);
        mfma_phase(smem, mx, mr, kb, q, Bh, Bl, acc);
    }
    __syncthreads();                 // all waves' J reads done before overwrite
    epilogue(smem, bias, wave, lane, acc);
    __syncthreads();                 // publish new J
}

__global__ __launch_bounds__(256, 4) void pinn_mfma(
    const float* __restrict__ gx, const float* __restrict__ gy, const float* __restrict__ gt,
    const float* __restrict__ W1, const float* __restrict__ b1,
    const float* __restrict__ b2, const float* __restrict__ b3,
    const float* __restrict__ bp1, const float* __restrict__ Wp2,
    const float* __restrict__ bd1, const float* __restrict__ Wd2,
    const float* __restrict__ bd2,
    const float* __restrict__ lam1p, const float* __restrict__ lam2p,
    const half_t* __restrict__ wsw, float* __restrict__ out) {
    extern __shared__ char smem[];
    const int t = threadIdx.x;
    const int wave = t >> 6, lane = t & 63;
    const int q = lane >> 4, nl = lane & 15;
    const int anl = nl < 13 ? nl : 12;   // packed-13 row clamp (dup rows ignored in C)
    const int base = blockIdx.x * TS;
    // wave-uniform B base offset (halfs) + per-lane offset: scalarized addressing
    const int wo = __builtin_amdgcn_readfirstlane(wave) * 16384;
    const int vo = lane * 8;

    // ---------------- Layer 1: (x,y,t) -> J1 ----------------
#pragma unroll 1
    for (int ii = 0; ii < 2; ++ii) {
        int p = ii * 256 + t;               // (sample, j-pair) 0..TS*128-1
        if (p < TS * 128) {
            int s = p >> 7, j = (p & 127) * 2;
            int gi = base + s; if (gi >= N_PTS) gi = N_PTS - 1;   // tail clamp
            float qx = gx[gi], qy = gy[gi], qt = gt[gi];
            float hv[2][13];
#pragma unroll
            for (int d = 0; d < 2; ++d) {
                int jj = j + d;
                float w0 = W1[3 * jj], w1 = W1[3 * jj + 1], w2 = W1[3 * jj + 2];
                float f = fast_tanh(w0 * qx + w1 * qy + w2 * qt + b1[jj]);
                float f1 = 1.f - f * f;
                float f2c = -2.f * f * f1;
                float f3c = -2.f * f1 * f1 + 4.f * f * f * f1;
                float* h = hv[d];
                h[0] = f; h[1] = f1 * w0; h[2] = f1 * w1; h[3] = f1 * w2;
                h[4] = f2c * w0 * w0; h[5] = f2c * w0 * w1; h[6] = f2c * w1 * w1;
                h[7] = f2c * w0 * w2; h[8] = f2c * w1 * w2;
                h[9]  = f3c * w0 * w0 * w0; h[10] = f3c * w0 * w0 * w1;
                h[11] = f3c * w0 * w1 * w1; h[12] = f3c * w1 * w1 * w1;
            }
#pragma unroll
            for (int c = 0; c < 13; ++c) {
                int m = s * 13 + c;
                int off = m * 512 + ((((j) >> 3) ^ (m & 15)) << 4) + ((j & 7) << 1);
                half_t hA = (half_t)hv[0][c], hB = (half_t)hv[1][c];
                *(hpair*)(smem + J_HI + off) = hpair{hA, hB};
                half_t lA = (half_t)(hv[0][c] - (float)hA);
                half_t lB = (half_t)(hv[1][c] - (float)hB);
                *(hpair*)(smem + J_LO + off) = hpair{lA, lB};
            }
        }
    }
    __syncthreads();

    floatx4 acc[3][4];

    // ---------------- Layers 2, 3 ----------------
    layer(smem, wsw + wo,          wsw + 65536 + wo,          b2,
          wave, lane, vo, q, anl, acc);
    layer(smem, wsw + 131072 + wo, wsw + 131072 + 65536 + wo, b3,
          wave, lane, vo, q, anl, acc);

    // ---------------- Data head (uses J3 comps 0..2), A read directly from J ----
    {
        // single M-tile: logical row r = nl = 4s+c -> J row s*13+c (c<3; dummies clamped)
        int sh = nl >> 2, ch = nl & 3;
        int sc = (sh < TS) ? sh : 0;             // TS=3: row 3 dup of sample 0 (unread)
        int mh = sc * 13 + ((ch == 3) ? 0 : ch);
        const int mxh = (mh & 15) << 4, mrh = mh * 512;
        floatx4 hacc[4];
#pragma unroll
        for (int nt = 0; nt < 4; ++nt) hacc[nt] = floatx4{0.f, 0.f, 0.f, 0.f};
        const half_t* Dhi = wsw + 3 * 131072 + wo;
        const half_t* Dlo = Dhi + 65536;
#pragma unroll 1
        for (int kb = 0; kb < 8; ++kb) {
            half8 Bh[4], Bl[4];
            load_B(Dhi, Dlo, vo, kb, Bh, Bl);
            const int a = mrh + ((((kb * 4 + q) << 4)) ^ mxh);
            half8 Ah = *(const half8*)(smem + J_HI + a);
            half8 Al = *(const half8*)(smem + J_LO + a);
#pragma unroll
            for (int nt = 0; nt < 4; ++nt) {
                hacc[nt] = __builtin_amdgcn_mfma_f32_16x16x32_f16(Ah, Bh[nt], hacc[nt], 0, 0, 0);
                hacc[nt] = __builtin_amdgcn_mfma_f32_16x16x32_f16(Ah, Bl[nt], hacc[nt], 0, 0, 0);
                hacc[nt] = __builtin_amdgcn_mfma_f32_16x16x32_f16(Al, Bh[nt], hacc[nt], 0, 0, 0);
            }
        }
        // head epilogue: C row = q*4 + reg -> sample s = q, comp c = reg (0..2 used)
        {
            float pp = 0, up = 0, vp = 0;
#pragma unroll
            for (int nt = 0; nt < 4; ++nt) {
                int n = wave * 64 + nt * 16 + nl;
                floatx4 a = hacc[nt];
                float f = fast_tanh(a.x + bd1[n]);
                float f1 = 1.f - f * f;
                float hdx = f1 * a.y, hdy = f1 * a.z;
                float w0 = Wd2[n], w1 = Wd2[HID + n];
                pp += w1 * f;
                up += w0 * hdy;
                vp -= w0 * hdx;
            }
            float* rb = (float*)(smem + REDBUF);
#pragma unroll
            for (int msk = 1; msk < 16; msk <<= 1) {
                pp += __shfl_xor(pp, msk, 64);
                up += __shfl_xor(up, msk, 64);
                vp += __shfl_xor(vp, msk, 64);
            }
            if (nl == 0) {                  // sample s = q (q==3 partials never read)
                rb[(q * 4 + wave) * 3 + 0] = pp;
                rb[(q * 4 + wave) * 3 + 1] = up;
                rb[(q * 4 + wave) * 3 + 2] = vp;
            }
        }
        __syncthreads();
        if (t < TS && base + t < N_PTS) {
            const float* rb = (const float*)(smem + REDBUF);
            float P = 0, U = 0, V = 0;
#pragma unroll
            for (int w = 0; w < 4; ++w) {
                P += rb[(t * 4 + w) * 3 + 0];
                U += rb[(t * 4 + w) * 3 + 1];
                V += rb[(t * 4 + w) * 3 + 2];
            }
            out[0 * N_PTS + base + t] = P + bd2[1];
            out[1 * N_PTS + base + t] = U;
            out[2 * N_PTS + base + t] = V;
        }
    }

    // ---------------- PDE-head layer Wp1 ----------------
    layer(smem, wsw + 2 * 131072 + wo, wsw + 2 * 131072 + 65536 + wo, bp1,
          wave, lane, vo, q, anl, acc);

    // ---------------- PDE reduction from J4 (vectorized: 16B chunk per lane) -------
    {
        int s = t >> 5, g = t & 31;
        if (s < TS) {
            // lane g owns k = g*8 .. g*8+7 (one 16 B chunk per row)
            floatx4 w0a = *(const floatx4*)(Wp2 + g * 8);
            floatx4 w0b = *(const floatx4*)(Wp2 + g * 8 + 4);
            floatx4 w1a = *(const floatx4*)(Wp2 + HID + g * 8);
            floatx4 w1b = *(const floatx4*)(Wp2 + HID + g * 8 + 4);
            float wr0[8] = {w0a.x, w0a.y, w0a.z, w0a.w, w0b.x, w0b.y, w0b.z, w0b.w};
            float wr1[8] = {w1a.x, w1a.y, w1a.z, w1a.w, w1b.x, w1b.y, w1b.z, w1b.w};
            float S[13], px = 0.f, py = 0.f;
#pragma unroll
            for (int c = 0; c < 13; ++c) {
                const int m = s * 13 + c;
                const int off = m * 512 + ((g ^ (m & 15)) << 4);
                half8 hv = *(const half8*)(smem + J_HI + off);
                half8 lv = *(const half8*)(smem + J_LO + off);
                float p = 0.f, p2 = 0.f;
#pragma unroll
                for (int e = 0; e < 8; ++e) {
                    float val = (float)hv[e] + (float)lv[e];
                    p += val * wr0[e];
                    if (c == 1 || c == 2) p2 += val * wr1[e];
                }
#pragma unroll
                for (int msk = 1; msk < 32; msk <<= 1) p += __shfl_xor(p, msk, 64);
                S[c] = p;
                if (c == 1) {
#pragma unroll
                    for (int msk = 1; msk < 32; msk <<= 1) p2 += __shfl_xor(p2, msk, 64);
                    px = p2;
                } else if (c == 2) {
#pragma unroll
                    for (int msk = 1; msk < 32; msk <<= 1) p2 += __shfl_xor(p2, msk, 64);
                    py = p2;
                }
            }
            if (g == 0 && base + s < N_PTS) {
                const float lam1 = lam1p[0], lam2 = lam2p[0];
                const float u_ = S[2], v_ = -S[1];
                const float u_x = S[5], u_y = S[6], u_t = S[8];
                const float v_x = -S[4], v_y = -S[5], v_t = -S[7];
                const float u_xx = S[10], u_yy = S[12];
                const float v_xx = -S[9], v_yy = -S[11];
                const float f_ = lam1 * (u_t + u_ * u_x + v_ * u_y) + px - lam2 * (u_xx + u_yy);
                const float g_ = lam1 * (v_t + u_ * v_x + v_ * v_y) + py - lam2 * (v_xx + v_yy);
                out[3 * N_PTS + base + s] = f_;
                out[4 * N_PTS + base + s] = g_;
            }
        }
    }
}

extern "C" void kernel_launch(void* const* d_in, const int* in_sizes, int n_in,
                              void* d_out, int out_size, void* d_ws, size_t ws_size,
                              hipStream_t stream) {
    const float* x   = (const float*)d_in[0];
    const float* y   = (const float*)d_in[1];
    const float* tt  = (const float*)d_in[2];
    const float* W1  = (const float*)d_in[6];
    const float* b1  = (const float*)d_in[7];
    const float* W2  = (const float*)d_in[8];
    const float* b2  = (const float*)d_in[9];
    const float* W3  = (const float*)d_in[10];
    const float* b3  = (const float*)d_in[11];
    const float* Wp1 = (const float*)d_in[12];
    const float* bp1 = (const float*)d_in[13];
    const float* Wp2 = (const float*)d_in[14];
    const float* Wd1 = (const float*)d_in[16];
    const float* bd1 = (const float*)d_in[17];
    const float* Wd2 = (const float*)d_in[18];
    const float* bd2 = (const float*)d_in[19];
    const float* l1  = (const float*)d_in[20];
    const float* l2  = (const float*)d_in[21];
    float* out = (float*)d_out;
    half_t* wsw = (half_t*)d_ws;   // needs 4 * 256 KB = 1 MB

    prep_w<<<256, 256, 0, stream>>>(W2, W3, Wp1, Wd1, wsw);

    (void)hipFuncSetAttribute((const void*)pinn_mfma,
                              hipFuncAttributeMaxDynamicSharedMemorySize,
                              (int)LDS_BYTES);
    pinn_mfma<<<(N_PTS + TS - 1) / TS, 256, LDS_BYTES, stream>>>(
        x, y, tt, W1, b1, b2, b3, bp1, Wp2, bd1, Wd2, bd2, l1, l2, wsw, out);
}

// Round 3
// 1120.096 us; speedup vs baseline: 1.3495x; 1.1410x over previous
//
#include <hip/hip_runtime.h>

// MFMA split-FP16 jet-propagation PINN.
// Jet comps: 0:val 1:x 2:y 3:t 4:xx 5:xy 6:yy 7:xt 8:yt 9:xxx 10:xxy 11:xyy 12:yyy
// J in LDS: PACKED rows m = sample*13 + comp, k = hidden neuron; f16 hi+lo planes.
// Row layout: 32 chunks of 8 f16 (16 B); phys chunk = logical ^ (m&15)  (bank swizzle).
// Per layer: U = J * W^T via mfma_f32_16x16x32_f16, 3 passes (hi*hi, hi*lo, lo*hi).
// R17 (1219 us steady): permlane transpose, xor-fold addressing, vector PDE tail.
// Audit: MfmaUtil 57 is real pipe occupancy; 19% of MFMA work is pad rows (13 rows
// in 16-row tiles, per-sample-aligned).
// R18: CROSS-SAMPLE TILE PACKING. TS=6 -> 78 packed rows fill 5 M-tiles at 97.5%
// (per-sample MFMA -15%); per-sample B-stream/barrier/prologue cost halves.
// LDS 80.2 KB -> 2 blocks/CU; VGPR headroom (launch_bounds(256,2)) spent on
// DOUBLE-BUFFERED B (hides per-kb L2 latency at 2 waves/SIMD). Epilogue jets
// samples as soon as their 13 rows are transposed (liveness ~100 VGPR).

#define N_PTS 65536
#define HID   256
#define TS    6
#define MROWS (TS * 13)           // 78 packed rows
#define MT    5                   // M-tiles of 16 rows

typedef _Float16 half_t;
typedef __attribute__((ext_vector_type(8))) _Float16 half8;
typedef __attribute__((ext_vector_type(4))) float floatx4;

#define J_HI   0
#define J_LO   39936              // 78 packed rows * 512 B per plane
#define REDBUF 79872              // 288 B head partials (6 samples * 4 waves * 3)
#define LDS_BYTES (REDBUF + 288)  // 80160 B -> 2 blocks/CU

struct alignas(4) hpair { half_t a, b; };

__device__ __forceinline__ float fast_tanh(float x) {
    float e = __builtin_amdgcn_exp2f(x * 2.885390081777927f);
    return 1.f - 2.f * __builtin_amdgcn_rcpf(e + 1.f);
}

__device__ __forceinline__ void tanh_jet(const float* u, float* h) {
    const float f  = fast_tanh(u[0]);
    const float f1 = 1.f - f * f;
    const float f2 = -2.f * f * f1;
    const float f3 = -2.f * f1 * f1 + 4.f * f * f * f1;
    const float ux = u[1], uy = u[2], ut = u[3];
    const float uxx = u[4], uxy = u[5], uyy = u[6], uxt = u[7], uyt = u[8];
    h[0] = f;
    h[1] = f1 * ux;  h[2] = f1 * uy;  h[3] = f1 * ut;
    h[4] = f2 * ux * ux + f1 * uxx;
    h[5] = f2 * ux * uy + f1 * uxy;
    h[6] = f2 * uy * uy + f1 * uyy;
    h[7] = f2 * ux * ut + f1 * uxt;
    h[8] = f2 * uy * ut + f1 * uyt;
    h[9]  = f3 * ux * ux * ux + 3.f * f2 * ux * uxx + f1 * u[9];
    h[10] = f3 * ux * ux * uy + f2 * (uxx * uy + 2.f * uxy * ux) + f1 * u[10];
    h[11] = f3 * ux * uy * uy + f2 * (uyy * ux + 2.f * uxy * uy) + f1 * u[11];
    h[12] = f3 * uy * uy * uy + 3.f * f2 * uy * uyy + f1 * u[12];
}

// ---- prep: split W2, W3, Wp1, Wd1 into f16 hi/lo planes, FRAGMENT-ORDERED ----
// (n,k) -> addr = ((ntile*8 + kb)*64 + q*16 + nl)*8 + e  -> wave loads 1 KB contiguous
__global__ void prep_w(const float* __restrict__ W2, const float* __restrict__ W3,
                       const float* __restrict__ Wp1, const float* __restrict__ Wd1,
                       half_t* __restrict__ ws) {
    int idx = blockIdx.x * 256 + threadIdx.x;
#pragma unroll
    for (int r = 0; r < 4; ++r) {
        int e = idx + r * 65536;
        int m = e >> 16, i = e & 65535;
        const float* src = (m == 0) ? W2 : (m == 1) ? W3 : (m == 2) ? Wp1 : Wd1;
        float w = src[i];
        half_t hi = (half_t)w;
        half_t lo = (half_t)(w - (float)hi);
        int n = i >> 8, k = i & 255;
        int addr = (((n >> 4) * 8 + (k >> 5)) * 64 + ((k >> 3) & 3) * 16 + (n & 15)) * 8
                   + (k & 7);
        ws[m * 131072 + addr] = hi;
        ws[m * 131072 + 65536 + addr] = lo;
    }
}

// coalesced fragment load, SCALAR base: bh/bl are wave-uniform (readfirstlane),
// vo = lane*8 halfs is the only per-lane term -> SGPR-base global_load.
__device__ __forceinline__ void load_B(const half_t* bh, const half_t* bl,
                                       int vo, int kb,
                                       half8 (&Bh)[4], half8 (&Bl)[4]) {
#pragma unroll
    for (int nt = 0; nt < 4; ++nt) {
        int off = nt * 4096 + kb * 512 + vo;   // halfs; nt,kb uniform
        Bh[nt] = *(const half8*)(bh + off);
        Bl[nt] = *(const half8*)(bl + off);
    }
}

// one kb step: MT A-tile pairs (precomputed row bases, xor-folded chunk), 60 MFMAs
__device__ __forceinline__ void mfma_phase(const char* __restrict__ smem,
                                           const int (&mx)[MT], const int (&mr)[MT],
                                           int kb, int q,
                                           const half8 (&Bh)[4], const half8 (&Bl)[4],
                                           floatx4 (&acc)[MT][4]) {
    const int kq = (kb * 4 + q) << 4;
#pragma unroll
    for (int mt = 0; mt < MT; ++mt) {
        const int a = mr[mt] + (kq ^ mx[mt]);
        half8 Ah = *(const half8*)(smem + J_HI + a);
        half8 Al = *(const half8*)(smem + J_LO + a);
#pragma unroll
        for (int nt = 0; nt < 4; ++nt) {
            acc[mt][nt] = __builtin_amdgcn_mfma_f32_16x16x32_f16(Ah, Bh[nt], acc[mt][nt], 0, 0, 0);
            acc[mt][nt] = __builtin_amdgcn_mfma_f32_16x16x32_f16(Ah, Bl[nt], acc[mt][nt], 0, 0, 0);
            acc[mt][nt] = __builtin_amdgcn_mfma_f32_16x16x32_f16(Al, Bh[nt], acc[mt][nt], 0, 0, 0);
        }
    }
}

// transpose epilogue via gfx950 dual-writeback permlane swaps (16 instr/tile).
// Cross-sample packing: tile mt covers packed rows 16mt..16mt+15; sample s is
// jetted as soon as rows 13s..13s+12 are transposed (tile (13s+12)/16). All
// indices static after unroll -> col[] stays in registers, dead entries freed.
__device__ __forceinline__ void epilogue(char* __restrict__ smem,
                                         const float* __restrict__ bias,
                                         int wave, int lane,
                                         floatx4 (&acc)[MT][4]) {
    const int n = wave * 64 + lane;
    const float bn = bias[n];
    const int lanebase = ((n >> 3) << 4) | ((n & 7) << 1);
    float col[MT * 16];
    // samples fully available after transposing tile mt: {0},{1},{2},{3},{4,5}
    const int s_lo[MT] = {0, 1, 2, 3, 4};
    const int s_hi[MT] = {0, 1, 2, 3, 5};
#pragma unroll
    for (int mt = 0; mt < MT; ++mt) {
        float tv[4][4];
#pragma unroll
        for (int j = 0; j < 4; ++j)
#pragma unroll
            for (int r = 0; r < 4; ++r) tv[j][r] = acc[mt][j][r];
#pragma unroll
        for (int r = 0; r < 4; ++r) {
            asm("v_permlane16_swap_b32 %0, %1" : "+v"(tv[0][r]), "+v"(tv[1][r]));
            asm("v_permlane16_swap_b32 %0, %1" : "+v"(tv[2][r]), "+v"(tv[3][r]));
            asm("v_permlane32_swap_b32 %0, %1" : "+v"(tv[0][r]), "+v"(tv[2][r]));
            asm("v_permlane32_swap_b32 %0, %1" : "+v"(tv[1][r]), "+v"(tv[3][r]));
        }
#pragma unroll
        for (int j = 0; j < 4; ++j)
#pragma unroll
            for (int r = 0; r < 4; ++r) col[mt * 16 + j * 4 + r] = tv[j][r];
#pragma unroll
        for (int s = s_lo[mt]; s <= s_hi[mt]; ++s) {
            float u[13], h[13];
#pragma unroll
            for (int c = 0; c < 13; ++c) u[c] = col[s * 13 + c];
            u[0] += bn;
            tanh_jet(u, h);
#pragma unroll
            for (int c = 0; c < 13; ++c) {
                const int m = s * 13 + c;
                const int off = m * 512 + (lanebase ^ ((m & 15) << 4));
                half_t hi = (half_t)h[c];
                *(half_t*)(smem + J_HI + off) = hi;
                *(half_t*)(smem + J_LO + off) = (half_t)(h[c] - (float)hi);
            }
        }
    }
}

// one full layer, FUSED: single K-sweep over all MT M-tiles with one B stream,
// DOUBLE-BUFFERED B (next kb's loads issue before current kb's MFMAs).
__device__ __forceinline__ void layer(char* __restrict__ smem,
                                      const half_t* bh, const half_t* bl,
                                      const float* __restrict__ bias,
                                      int wave, int lane, int vo, int q, int nl,
                                      floatx4 (&acc)[MT][4]) {
    int mx[MT], mr[MT];
#pragma unroll
    for (int mt = 0; mt < MT; ++mt) {
        int m = mt * 16 + nl;
        if (m > MROWS - 1) m = MROWS - 1;   // tile 4 clamp (C rows 78/79 discarded)
        mx[mt] = (m & 15) << 4;
        mr[mt] = m * 512;
    }
    half8 B0h[4], B0l[4], B1h[4], B1l[4];
    load_B(bh, bl, vo, 0, B0h, B0l);
#pragma unroll
    for (int mt = 0; mt < MT; ++mt)
#pragma unroll
        for (int nt = 0; nt < 4; ++nt) acc[mt][nt] = floatx4{0.f, 0.f, 0.f, 0.f};
#pragma unroll 1
    for (int kb = 0; kb < 8; kb += 2) {
        load_B(bh, bl, vo, kb + 1, B1h, B1l);
        mfma_phase(smem, mx, mr, kb, q, B0h, B0l, acc);
        if (kb + 2 < 8) load_B(bh, bl, vo, kb + 2, B0h, B0l);
        mfma_phase(smem, mx, mr, kb + 1, q, B1h, B1l, acc);
    }
    __syncthreads();                 // all waves' J reads done before overwrite
    epilogue(smem, bias, wave, lane, acc);
    __syncthreads();                 // publish new J
}

__global__ __launch_bounds__(256, 2) void pinn_mfma(
    const float* __restrict__ gx, const float* __restrict__ gy, const float* __restrict__ gt,
    const float* __restrict__ W1, const float* __restrict__ b1,
    const float* __restrict__ b2, const float* __restrict__ b3,
    const float* __restrict__ bp1, const float* __restrict__ Wp2,
    const float* __restrict__ bd1, const float* __restrict__ Wd2,
    const float* __restrict__ bd2,
    const float* __restrict__ lam1p, const float* __restrict__ lam2p,
    const half_t* __restrict__ wsw, float* __restrict__ out) {
    extern __shared__ char smem[];
    const int t = threadIdx.x;
    const int wave = t >> 6, lane = t & 63;
    const int q = lane >> 4, nl = lane & 15;
    const int base = blockIdx.x * TS;
    // wave-uniform B base offset (halfs) + per-lane offset: scalarized addressing
    const int wo = __builtin_amdgcn_readfirstlane(wave) * 16384;
    const int vo = lane * 8;

    // ---------------- Layer 1: (x,y,t) -> J1 ----------------
#pragma unroll 1
    for (int ii = 0; ii < 3; ++ii) {
        int p = ii * 256 + t;               // (sample, j-pair) 0..TS*128-1 (=768 exact)
        int s = p >> 7, j = (p & 127) * 2;
        int gi = base + s; if (gi >= N_PTS) gi = N_PTS - 1;   // tail clamp
        float qx = gx[gi], qy = gy[gi], qt = gt[gi];
        float hv[2][13];
#pragma unroll
        for (int d = 0; d < 2; ++d) {
            int jj = j + d;
            float w0 = W1[3 * jj], w1 = W1[3 * jj + 1], w2 = W1[3 * jj + 2];
            float f = fast_tanh(w0 * qx + w1 * qy + w2 * qt + b1[jj]);
            float f1 = 1.f - f * f;
            float f2c = -2.f * f * f1;
            float f3c = -2.f * f1 * f1 + 4.f * f * f * f1;
            float* h = hv[d];
            h[0] = f; h[1] = f1 * w0; h[2] = f1 * w1; h[3] = f1 * w2;
            h[4] = f2c * w0 * w0; h[5] = f2c * w0 * w1; h[6] = f2c * w1 * w1;
            h[7] = f2c * w0 * w2; h[8] = f2c * w1 * w2;
            h[9]  = f3c * w0 * w0 * w0; h[10] = f3c * w0 * w0 * w1;
            h[11] = f3c * w0 * w1 * w1; h[12] = f3c * w1 * w1 * w1;
        }
#pragma unroll
        for (int c = 0; c < 13; ++c) {
            int m = s * 13 + c;
            int off = m * 512 + ((((j) >> 3) ^ (m & 15)) << 4) + ((j & 7) << 1);
            half_t hA = (half_t)hv[0][c], hB = (half_t)hv[1][c];
            *(hpair*)(smem + J_HI + off) = hpair{hA, hB};
            half_t lA = (half_t)(hv[0][c] - (float)hA);
            half_t lB = (half_t)(hv[1][c] - (float)hB);
            *(hpair*)(smem + J_LO + off) = hpair{lA, lB};
        }
    }
    __syncthreads();

    floatx4 acc[MT][4];

    // ---------------- Layers 2, 3 ----------------
    layer(smem, wsw + wo,          wsw + 65536 + wo,          b2,
          wave, lane, vo, q, nl, acc);
    layer(smem, wsw + 131072 + wo, wsw + 131072 + 65536 + wo, b3,
          wave, lane, vo, q, nl, acc);

    // ---------------- Data head (uses J3 comps 0..2), A read directly from J ----
    {
        // two head tiles, sample-aligned rows: tile ht row r = 4*sl + c,
        // sample s = ht*4 + sl, comp c (c==3 dummy). Row per lane: r = nl.
        int ch = (nl & 3) == 3 ? 0 : (nl & 3);
        int mh[2];
        mh[0] = (nl >> 2) * 13 + ch;
        {
            int s1 = 4 + (nl >> 2);
            mh[1] = (s1 < TS) ? s1 * 13 + ch : 52;   // clamp (results discarded)
        }
        floatx4 hacc[2][4];
#pragma unroll
        for (int ht = 0; ht < 2; ++ht)
#pragma unroll
            for (int nt = 0; nt < 4; ++nt) hacc[ht][nt] = floatx4{0.f, 0.f, 0.f, 0.f};
        const half_t* Dhi = wsw + 3 * 131072 + wo;
        const half_t* Dlo = Dhi + 65536;
#pragma unroll 1
        for (int kb = 0; kb < 8; ++kb) {
            half8 Bh[4], Bl[4];
            load_B(Dhi, Dlo, vo, kb, Bh, Bl);
#pragma unroll
            for (int ht = 0; ht < 2; ++ht) {
                const int a = mh[ht] * 512 + ((((kb * 4 + q) << 4)) ^ ((mh[ht] & 15) << 4));
                half8 Ah = *(const half8*)(smem + J_HI + a);
                half8 Al = *(const half8*)(smem + J_LO + a);
#pragma unroll
                for (int nt = 0; nt < 4; ++nt) {
                    hacc[ht][nt] = __builtin_amdgcn_mfma_f32_16x16x32_f16(Ah, Bh[nt], hacc[ht][nt], 0, 0, 0);
                    hacc[ht][nt] = __builtin_amdgcn_mfma_f32_16x16x32_f16(Ah, Bl[nt], hacc[ht][nt], 0, 0, 0);
                    hacc[ht][nt] = __builtin_amdgcn_mfma_f32_16x16x32_f16(Al, Bh[nt], hacc[ht][nt], 0, 0, 0);
                }
            }
        }
        // head epilogue: C row = 4*sl + c -> sample ht*4 + q, comp = reg (0..2 used)
        float* rb = (float*)(smem + REDBUF);
#pragma unroll
        for (int ht = 0; ht < 2; ++ht) {
            float pp = 0, up = 0, vp = 0;
#pragma unroll
            for (int nt = 0; nt < 4; ++nt) {
                int n = wave * 64 + nt * 16 + nl;
                floatx4 a = hacc[ht][nt];
                float f = fast_tanh(a.x + bd1[n]);
                float f1 = 1.f - f * f;
                float hdx = f1 * a.y, hdy = f1 * a.z;
                float w0 = Wd2[n], w1 = Wd2[HID + n];
                pp += w1 * f;
                up += w0 * hdy;
                vp -= w0 * hdx;
            }
#pragma unroll
            for (int msk = 1; msk < 16; msk <<= 1) {
                pp += __shfl_xor(pp, msk, 64);
                up += __shfl_xor(up, msk, 64);
                vp += __shfl_xor(vp, msk, 64);
            }
            int s = ht * 4 + q;
            if (nl == 0 && s < TS) {
                rb[(s * 4 + wave) * 3 + 0] = pp;
                rb[(s * 4 + wave) * 3 + 1] = up;
                rb[(s * 4 + wave) * 3 + 2] = vp;
            }
        }
        __syncthreads();
        if (t < TS && base + t < N_PTS) {
            float P = 0, U = 0, V = 0;
#pragma unroll
            for (int w = 0; w < 4; ++w) {
                P += rb[(t * 4 + w) * 3 + 0];
                U += rb[(t * 4 + w) * 3 + 1];
                V += rb[(t * 4 + w) * 3 + 2];
            }
            out[0 * N_PTS + base + t] = P + bd2[1];
            out[1 * N_PTS + base + t] = U;
            out[2 * N_PTS + base + t] = V;
        }
    }

    // ---------------- PDE-head layer Wp1 ----------------
    layer(smem, wsw + 2 * 131072 + wo, wsw + 2 * 131072 + 65536 + wo, bp1,
          wave, lane, vo, q, nl, acc);

    // ---------------- PDE reduction from J4 (vectorized: 16B chunk per lane) -------
    {
        int s = t >> 5, g = t & 31;
        if (s < TS) {
            // lane g owns k = g*8 .. g*8+7 (one 16 B chunk per row)
            floatx4 w0a = *(const floatx4*)(Wp2 + g * 8);
            floatx4 w0b = *(const floatx4*)(Wp2 + g * 8 + 4);
            floatx4 w1a = *(const floatx4*)(Wp2 + HID + g * 8);
            floatx4 w1b = *(const floatx4*)(Wp2 + HID + g * 8 + 4);
            float wr0[8] = {w0a.x, w0a.y, w0a.z, w0a.w, w0b.x, w0b.y, w0b.z, w0b.w};
            float wr1[8] = {w1a.x, w1a.y, w1a.z, w1a.w, w1b.x, w1b.y, w1b.z, w1b.w};
            float S[13], px = 0.f, py = 0.f;
#pragma unroll
            for (int c = 0; c < 13; ++c) {
                const int m = s * 13 + c;
                const int off = m * 512 + ((g ^ (m & 15)) << 4);
                half8 hv = *(const half8*)(smem + J_HI + off);
                half8 lv = *(const half8*)(smem + J_LO + off);
                float p = 0.f, p2 = 0.f;
#pragma unroll
                for (int e = 0; e < 8; ++e) {
                    float val = (float)hv[e] + (float)lv[e];
                    p += val * wr0[e];
                    if (c == 1 || c == 2) p2 += val * wr1[e];
                }
#pragma unroll
                for (int msk = 1; msk < 32; msk <<= 1) p += __shfl_xor(p, msk, 64);
                S[c] = p;
                if (c == 1) {
#pragma unroll
                    for (int msk = 1; msk < 32; msk <<= 1) p2 += __shfl_xor(p2, msk, 64);
                    px = p2;
                } else if (c == 2) {
#pragma unroll
                    for (int msk = 1; msk < 32; msk <<= 1) p2 += __shfl_xor(p2, msk, 64);
                    py = p2;
                }
            }
            if (g == 0 && base + s < N_PTS) {
                const float lam1 = lam1p[0], lam2 = lam2p[0];
                const float u_ = S[2], v_ = -S[1];
                const float u_x = S[5], u_y = S[6], u_t = S[8];
                const float v_x = -S[4], v_y = -S[5], v_t = -S[7];
                const float u_xx = S[10], u_yy = S[12];
                const float v_xx = -S[9], v_yy = -S[11];
                const float f_ = lam1 * (u_t + u_ * u_x + v_ * u_y) + px - lam2 * (u_xx + u_yy);
                const float g_ = lam1 * (v_t + u_ * v_x + v_ * v_y) + py - lam2 * (v_xx + v_yy);
                out[3 * N_PTS + base + s] = f_;
                out[4 * N_PTS + base + s] = g_;
            }
        }
    }
}

extern "C" void kernel_launch(void* const* d_in, const int* in_sizes, int n_in,
                              void* d_out, int out_size, void* d_ws, size_t ws_size,
                              hipStream_t stream) {
    const float* x   = (const float*)d_in[0];
    const float* y   = (const float*)d_in[1];
    const float* tt  = (const float*)d_in[2];
    const float* W1  = (const float*)d_in[6];
    const float* b1  = (const float*)d_in[7];
    const float* W2  = (const float*)d_in[8];
    const float* b2  = (const float*)d_in[9];
    const float* W3  = (const float*)d_in[10];
    const float* b3  = (const float*)d_in[11];
    const float* Wp1 = (const float*)d_in[12];
    const float* bp1 = (const float*)d_in[13];
    const float* Wp2 = (const float*)d_in[14];
    const float* Wd1 = (const float*)d_in[16];
    const float* bd1 = (const float*)d_in[17];
    const float* Wd2 = (const float*)d_in[18];
    const float* bd2 = (const float*)d_in[19];
    const float* l1  = (const float*)d_in[20];
    const float* l2  = (const float*)d_in[21];
    float* out = (float*)d_out;
    half_t* wsw = (half_t*)d_ws;   // needs 4 * 256 KB = 1 MB

    prep_w<<<256, 256, 0, stream>>>(W2, W3, Wp1, Wd1, wsw);

    (void)hipFuncSetAttribute((const void*)pinn_mfma,
                              hipFuncAttributeMaxDynamicSharedMemorySize,
                              (int)LDS_BYTES);
    pinn_mfma<<<(N_PTS + TS - 1) / TS, 256, LDS_BYTES, stream>>>(
        x, y, tt, W1, b1, b2, b3, bp1, Wp2, bd1, Wd2, bd2, l1, l2, wsw, out);
}